// Round 8
// baseline (153.438 us; speedup 1.0000x reference)
//
#include <hip/hip_runtime.h>

// Autoregressive LSTM log-prob via MFMA — de-lockstepped 2-WG/CU design.
// B=4096, L=256, H=32, D=2. 512 WGs x 256 threads (4 waves), 8 batches/WG.
// gates^T = Wh^T @ h^T. Batch cols duplicated into both N-halves of the
// 16x16x32 tile; rows 4*oct+{0,1} of each gate tile carry units 8*oct+w and
// 8*oct+4+w, so every lane extracts exactly ONE cell from acc reg (n>>3).
// Head logits ride in the unused reg-2 rows of tile 0 (rows 2,6 = Wo cols).
// Per-SIMD issue identical to R7, but the 2 waves/SIMD belong to DIFFERENT
// workgroups with independent barriers -> stalls de-lockstepped.
// Scales folded (i,f,o: -log2e; g: +2log2e); bias in MFMA C regs 0/1.
// Cell chain uses combined rcp: R = 1/((1+ei)(1+eg)(1+ef)).

typedef __attribute__((ext_vector_type(8))) short bf16x8;
typedef __attribute__((ext_vector_type(4))) float f32x4;

#define LOG2E 1.4426950408889634f
#define LN2   0.6931471805599453f

__device__ __forceinline__ float fexp2(float x) { return __builtin_amdgcn_exp2f(x); }
__device__ __forceinline__ float flog2(float x) { return __builtin_amdgcn_logf(x); }
__device__ __forceinline__ float frcp(float x)  { return __builtin_amdgcn_rcpf(x); }

__device__ __forceinline__ float fsig(float x)   { return frcp(1.f + fexp2(-LOG2E * x)); }
__device__ __forceinline__ float ftanh_(float x) { return 1.f - 2.f * frcp(fexp2(2.f * LOG2E * x) + 1.f); }
__device__ __forceinline__ float felu(float x)   { return x > 0.f ? x : fexp2(LOG2E * x) - 1.f; }

__device__ __forceinline__ unsigned short f2bf(float f) {   // RNE f32->bf16
    unsigned u = __builtin_bit_cast(unsigned, f);
    u = (u + 0x7FFFu + ((u >> 16) & 1u)) >> 16;
    return (unsigned short)u;
}

constexpr int Bsz = 4096;

__global__ __launch_bounds__(256, 2) void lstm_mfma2wg(
    const int*   __restrict__ x,    // [B, 256]
    const float* __restrict__ Wi,   // [2, 128]
    const float* __restrict__ Wh,   // [32, 128]
    const float* __restrict__ bh,   // [128]
    const float* __restrict__ Wo,   // [32, 2]
    const float* __restrict__ bo,   // [2]
    float*       __restrict__ out)  // [B]
{
    const int tid  = threadIdx.x;
    const int w    = tid >> 6;      // wave 0..3
    const int lane = tid & 63;
    const int n    = lane & 15;     // D col (batch, duplicated)
    const int oct  = lane >> 4;
    const int m    = n & 7;         // batch
    const int sel  = n >> 3;        // which acc reg holds my cell (0/1)
    const int b0   = blockIdx.x * 8;

    __shared__ char  spinT[8][260];      // [batch][t] bytes, padded row
    __shared__ float Sbuf[256 * 8 * 2];  // raw logits [t][batch][d]
    __shared__ short hbuf[2][8][40];     // h dbuf, row stride 80 B (16B aligned)
    __shared__ float red[32][8];

    // ---- stage spins: 256 threads x 8 bytes ----
    {
        const int bl = tid >> 5;         // batch 0..7
        const int c8 = (tid & 31) * 8;
        const int4* src = reinterpret_cast<const int4*>(x + (b0 + bl) * 256 + c8);
        const int4 v0 = src[0], v1 = src[1];
        const int p0 = (v0.x & 1) | ((v0.y & 1) << 8) | ((v0.z & 1) << 16) | ((v0.w & 1) << 24);
        const int p1 = (v1.x & 1) | ((v1.y & 1) << 8) | ((v1.z & 1) << 16) | ((v1.w & 1) << 24);
        *reinterpret_cast<int*>(&spinT[bl][c8])     = p0;
        *reinterpret_cast<int*>(&spinT[bl][c8 + 4]) = p1;
    }

    // ---- A-fragments. Lane (n,oct) builds A row n, k-slots 8*oct+j (unit id).
    // Row r = 4*oN + rho: rho 0/1 -> gate cols of units 8*oN + 4*rho + w;
    // rho==2 (tile 0 only): oN==0 -> Wo[:,0], oN==1 -> Wo[:,1]; else zero.
    const int rho = n & 3;
    const int oN  = n >> 2;
    bf16x8 wfrag[4];
#pragma unroll
    for (int q = 0; q < 4; ++q) {
        const float gs = (q == 2) ? 2.f * LOG2E : -LOG2E;
#pragma unroll
        for (int j = 0; j < 8; ++j) {
            const int u = 8 * oct + j;
            float v = 0.f;
            if (rho < 2)                 v = gs * Wh[u * 128 + 32 * q + 8 * oN + 4 * rho + w];
            else if (rho == 2 && q == 0 && oN < 2) v = Wo[u * 2 + oN];
            wfrag[q][j] = (short)f2bf(v);
        }
    }

    // ---- this lane's cell + scaled biases for C regs 0 (U0) and 1 (U1) ----
    const int ucell = 8 * oct + 4 * sel + w;
    float2 bv0[4], bvd[4];
#pragma unroll
    for (int q = 0; q < 4; ++q) {
        const float gs = (q == 2) ? 2.f * LOG2E : -LOG2E;
        const int c0 = 32 * q + 8 * oct + w;        // U0 = 8*oct + w
        const int c1 = c0 + 4;                      // U1 = 8*oct + 4 + w
        bv0[q].x = gs * (bh[c0] + Wi[c0]);
        bvd[q].x = gs * (Wi[128 + c0] - Wi[c0]);
        bv0[q].y = gs * (bh[c1] + Wi[c1]);
        bvd[q].y = gs * (Wi[128 + c1] - Wi[c1]);
    }
    const float bo0 = bo[0], bo1 = bo[1];

    // ---- peel t=0: input zeros, h=c=0 -> gates = bh ----
    float c = fsig(bh[ucell]) * ftanh_(bh[64 + ucell]);
    hbuf[0][m][ucell] = (short)f2bf(fsig(bh[96 + ucell]) * ftanh_(c));
    __syncthreads();

    const f32x4 zero4 = { 0.f, 0.f, 0.f, 0.f };
    f32x4 ccq[4] = { zero4, zero4, zero4, zero4 };
    float spf = (float)spinT[m][0];

    for (int t = 1; t < 256; ++t) {
        const bf16x8 hfrag =
            *reinterpret_cast<const bf16x8*>(&hbuf[(t + 1) & 1][m][8 * oct]);

        // biases (spin_{t-1} selects Wi row) into C regs 0,1
#pragma unroll
        for (int q = 0; q < 4; ++q) {
            ccq[q][0] = fmaf(spf, bvd[q].x, bv0[q].x);
            ccq[q][1] = fmaf(spf, bvd[q].y, bv0[q].y);
        }

        f32x4 acc[4];
#pragma unroll
        for (int q = 0; q < 4; ++q)
            acc[q] = __builtin_amdgcn_mfma_f32_16x16x32_bf16(wfrag[q], hfrag, ccq[q], 0, 0, 0);

        // head logits of step t-1 live in acc[0][2] (rows 2,6 -> S0,S1)
        if (w == 0 && oct < 2 && n < 8)
            Sbuf[((t - 1) * 8 + m) * 2 + oct] = acc[0][2];

        const float spn = (float)spinT[m][t];   // prefetch next spin

        // my gates: reg `sel`
        const float g0 = sel ? acc[0][1] : acc[0][0];
        const float g1 = sel ? acc[1][1] : acc[1][0];
        const float g2 = sel ? acc[2][1] : acc[2][0];
        const float g3 = sel ? acc[3][1] : acc[3][0];

        // cell update: e_i=e^{-i}, e_f=e^{-f}, e_g=e^{2g}, e_o=e^{-o}
        {
            const float ei = fexp2(g0), ef = fexp2(g1);
            const float eg = fexp2(g2), eo = fexp2(g3);
            const float P = (1.f + ei) * (1.f + eg);
            const float Q = 1.f + ef;
            const float R = frcp(P * Q);            // combined reciprocal
            const float gf  = P * R;                // 1/(1+ef)
            const float igt = (eg - 1.f) * Q * R;   // sig(i)*tanh(g)
            c = fmaf(gf, c, igt);
            const float ec = fexp2(2.f * LOG2E * c);
            const float h  = (ec - 1.f) * frcp((1.f + eo) * (1.f + ec));
            hbuf[t & 1][m][ucell] = (short)f2bf(h);
        }

        spf = spn;
        __syncthreads();
    }

    // ---- tail: head logits of step 255 (h_255 in hbuf[1]) ----
    if (w == 0) {
        const bf16x8 hfrag = *reinterpret_cast<const bf16x8*>(&hbuf[1][m][8 * oct]);
        const f32x4 hacc =
            __builtin_amdgcn_mfma_f32_16x16x32_bf16(wfrag[0], hfrag, zero4, 0, 0, 0);
        if (oct < 2 && n < 8)
            Sbuf[(255 * 8 + m) * 2 + oct] = hacc[2];
    }
    __syncthreads();

    // ---- post phase: ELU + log-softmax + time reduction ----
    {
        const int m2 = tid & 7;
        const int t0 = (tid >> 3) * 8;   // 32 chunks of 8 steps
        float lp = 0.f;
#pragma unroll
        for (int i = 0; i < 8; ++i) {
            const int t = t0 + i;
            const float S0 = Sbuf[(t * 8 + m2) * 2 + 0] + bo0;
            const float S1 = Sbuf[(t * 8 + m2) * 2 + 1] + bo1;
            const int sp = spinT[m2][t];
            const float o0 = felu(S0);
            const float o1 = felu(S1);
            const float mx = fmaxf(o0, o1), mn = fminf(o0, o1);
            const float lse = mx + LN2 * flog2(1.f + fexp2(LOG2E * (mn - mx)));
            lp += (sp ? o1 : o0) - lse;
        }
        red[tid >> 3][m2] = lp;
    }
    __syncthreads();
    if (tid < 8) {
        float s = 0.f;
#pragma unroll
        for (int g = 0; g < 32; ++g) s += red[g][tid];
        out[b0 + tid] = 0.5f * s;
    }
}

extern "C" void kernel_launch(void* const* d_in, const int* in_sizes, int n_in,
                              void* d_out, int out_size, void* d_ws, size_t ws_size,
                              hipStream_t stream) {
    const int*   x  = (const int*)d_in[0];
    const float* Wi = (const float*)d_in[1];
    const float* Wh = (const float*)d_in[2];
    const float* bh = (const float*)d_in[3];
    const float* Wo = (const float*)d_in[4];
    const float* bo = (const float*)d_in[5];
    float* out = (float*)d_out;

    lstm_mfma2wg<<<dim3(Bsz / 8), dim3(256), 0, stream>>>(x, Wi, Wh, bh, Wo, bo, out);
}